// Round 3
// baseline (288.556 us; speedup 1.0000x reference)
//
#include <hip/hip_runtime.h>
#include <hip/hip_bf16.h>
#include <math.h>

#define B_  2
#define S_  2048
#define H_  16
#define D_  64
#define STR 72   // padded LDS row stride (shorts)

typedef __attribute__((ext_vector_type(8))) short bf16x8_t;
typedef __attribute__((ext_vector_type(4))) float f32x4_t;

__device__ __forceinline__ unsigned short f2bf(float f) {
    __hip_bfloat16 h = __float2bfloat16(f);
    return __builtin_bit_cast(unsigned short, h);
}

// ---------------- kernel 1: fused prep ----------------
// Per block: one (b,h) head, 128 s-rows. Q,K: rotary * xpos-scale * folded decay
// (q *= gamma^s, k *= gamma^-s), fp32 -> bf16, (B,S,H*64) -> (B,H,S,64).
// V: transpose+cast to (B,H,64,S).
__global__ __launch_bounds__(256) void prep_kernel(const float* __restrict__ Q,
                                                   const float* __restrict__ K,
                                                   const float* __restrict__ V,
                                                   unsigned short* __restrict__ qb,
                                                   unsigned short* __restrict__ kb,
                                                   unsigned short* __restrict__ vt) {
    __shared__ float tile[64 * 65];
    int t   = threadIdx.x;
    int bh  = blockIdx.x >> 4;    // 0..31
    int scn = blockIdx.x & 15;    // 0..15
    int b = bh >> 4, hh = bh & 15;
    int s0 = scn * 128;

    float lnv   = -3.4657359027997265f + (float)hh * (-0.18483924814931874f);
    float gamma = 1.0f - expf(lnv);
    float l2g   = log2f(gamma);

    // ---- phase A: xpos for Q and K (head hh, rows s0..s0+127) ----
#pragma unroll
    for (int it = 0; it < 16; ++it) {
        int idx = it * 256 + t;        // 4096 items = 128 s x 32 pairs
        int i  = idx & 31;             // rotary pair index
        int sl = idx >> 5;
        int s  = s0 + sl;
        float pos = (float)s;

        float bsc  = (2.0f * (float)i + 25.6f) / 89.6f;
        float xsc  = exp2f(log2f(bsc) * pos * (1.0f / 512.0f));
        float invf = exp2f(-(float)i * (13.287712379549449f / 32.0f));
        float ang  = pos * invf;
        // one-step Cody-Waite reduction (k <= ~326, err ~1e-4 rad: fine for bf16)
        float kq = rintf(ang * 0.15915494309189535f);
        float r  = fmaf(kq, -6.2831853071795865f, ang);
        float sn = sinf(r), cs = cosf(r);

        float gs  = exp2f(pos * l2g);    // gamma^s
        float gsi = exp2f(-pos * l2g);   // gamma^-s
        float rxs = 1.0f / xsc;

        float cq = cs * xsc * gs,  sq = sn * xsc * gs;
        float ck = cs * rxs * gsi, sk = sn * rxs * gsi;

        long inIdx = ((long)(b * S_ + s)) * 1024 + hh * 64 + 2 * i;
        float2 xq = *(const float2*)(Q + inIdx);
        float2 xk = *(const float2*)(K + inIdx);
        float q0 = xq.x * cq - xq.y * sq, q1 = xq.y * cq + xq.x * sq;
        float k0 = xk.x * ck - xk.y * sk, k1 = xk.y * ck + xk.x * sk;

        long outIdx = ((long)(bh * S_ + s)) * 64 + 2 * i;
        *(unsigned int*)(qb + outIdx) = (unsigned)f2bf(q0) | ((unsigned)f2bf(q1) << 16);
        *(unsigned int*)(kb + outIdx) = (unsigned)f2bf(k0) | ((unsigned)f2bf(k1) << 16);
    }

    // ---- phase B: V transpose, two 64-row halves ----
#pragma unroll
    for (int half = 0; half < 2; ++half) {
        __syncthreads();
        int sb = s0 + half * 64;
#pragma unroll
        for (int it = 0; it < 4; ++it) {
            int f  = it * 256 + t;
            int sl = f >> 4;
            int d4 = f & 15;
            float4 v = *(const float4*)(V + ((long)(b * S_ + sb + sl)) * 1024 + hh * 64 + d4 * 4);
            tile[sl * 65 + d4 * 4 + 0] = v.x;
            tile[sl * 65 + d4 * 4 + 1] = v.y;
            tile[sl * 65 + d4 * 4 + 2] = v.z;
            tile[sl * 65 + d4 * 4 + 3] = v.w;
        }
        __syncthreads();
        int d = t >> 2, c = t & 3;
        unsigned int pk[8];
#pragma unroll
        for (int jj = 0; jj < 8; ++jj) {
            float f0 = tile[(c * 16 + 2 * jj + 0) * 65 + d];
            float f1 = tile[(c * 16 + 2 * jj + 1) * 65 + d];
            pk[jj] = (unsigned int)f2bf(f0) | ((unsigned int)f2bf(f1) << 16);
        }
        unsigned short* outp = vt + ((long)(bh * 64 + d)) * S_ + sb + c * 16;
        ((uint4*)outp)[0] = make_uint4(pk[0], pk[1], pk[2], pk[3]);
        ((uint4*)outp)[1] = make_uint4(pk[4], pk[5], pk[6], pk[7]);
    }
}

// ---------------- kernel 2: retention, one wave per block ----------------
// 2048 blocks x 64 threads. Wave owns 32 q-rows. __launch_bounds__(64,2) caps
// VGPR at 256 so ALL K/V fragments load in one batch (R2 was VGPR-starved at 56
// -> serialized loads). Register double-buffer prefetches tile kt+1 during kt.
#define LOAD_TILES(dstK, dstV, kt_)                                                        \
    {                                                                                      \
        const unsigned short* kp_ = kB + (kt_) * 64 * 64;                                  \
        const unsigned short* vp_ = vB + (kt_) * 64;                                       \
        _Pragma("unroll") for (int nt = 0; nt < 4; ++nt)                                   \
            _Pragma("unroll") for (int kk = 0; kk < 2; ++kk) {                             \
                dstK[nt][kk] =                                                             \
                    *(const bf16x8_t*)(kp_ + (nt * 16 + l16) * 64 + kk * 32 + quad * 8);   \
                dstV[nt][kk] = *(const bf16x8_t*)(vp_ + (long)(nt * 16 + l16) * S_ +       \
                                                  kk * 32 + quad * 8);                     \
            }                                                                              \
    }

__global__ __launch_bounds__(64, 2) void retention_kernel(const unsigned short* __restrict__ qb,
                                                          const unsigned short* __restrict__ kb,
                                                          const unsigned short* __restrict__ vt,
                                                          float* __restrict__ out) {
    __shared__ __align__(16) unsigned short Ss[32 * STR];   // 4.5 KB, wave-private

    int lane = threadIdx.x, quad = lane >> 4, l16 = lane & 15;
    int bh = blockIdx.x & 31;
    int j  = blockIdx.x >> 5;                     // 0..63
    int qg = (j < 32) ? (2 * j) : (127 - 2 * j);  // anti-correlated lengths
    int b = bh >> 4, hh = bh & 15;
    int q0 = qg * 32;
    int ktmax = qg >> 1;
    int odd = qg & 1;

    const unsigned short* qB = qb + ((long)bh * S_ + q0) * 64;
    const unsigned short* kB = kb + (long)bh * S_ * 64;
    const unsigned short* vB = vt + (long)bh * 64 * S_;

    bf16x8_t aQ[2][2];
#pragma unroll
    for (int m = 0; m < 2; ++m)
#pragma unroll
        for (int kk = 0; kk < 2; ++kk)
            aQ[m][kk] = *(const bf16x8_t*)(qB + (m * 16 + l16) * 64 + kk * 32 + quad * 8);

    f32x4_t acc[2][4];
#pragma unroll
    for (int m = 0; m < 2; ++m)
#pragma unroll
        for (int nd = 0; nd < 4; ++nd) acc[m][nd] = (f32x4_t){0.f, 0.f, 0.f, 0.f};

    bf16x8_t bK[2][4][2], bV[2][4][2];
    LOAD_TILES(bK[0], bV[0], 0);     // prologue: tile 0
    int cur = 0;

#pragma unroll 2
    for (int kt = 0; kt < ktmax; ++kt) {
        // ---- S = Q K^T on current buffer ----
        f32x4_t sc[2][4];
#pragma unroll
        for (int m = 0; m < 2; ++m)
#pragma unroll
            for (int nt = 0; nt < 4; ++nt) sc[m][nt] = (f32x4_t){0.f, 0.f, 0.f, 0.f};
#pragma unroll
        for (int kk = 0; kk < 2; ++kk)
#pragma unroll
            for (int m = 0; m < 2; ++m)
#pragma unroll
                for (int nt = 0; nt < 4; ++nt)
                    sc[m][nt] = __builtin_amdgcn_mfma_f32_16x16x32_bf16(
                        aQ[m][kk], bK[cur][nt][kk], sc[m][nt], 0, 0, 0);

        // ---- prefetch next tile (kt+1 <= ktmax valid) into alternate buffer ----
        LOAD_TILES(bK[1 - cur], bV[1 - cur], kt + 1);

        // ---- C-layout -> bf16 -> LDS -> A-layout ----
#pragma unroll
        for (int m = 0; m < 2; ++m)
#pragma unroll
            for (int nt = 0; nt < 4; ++nt)
#pragma unroll
                for (int r = 0; r < 4; ++r)
                    Ss[(m * 16 + quad * 4 + r) * STR + nt * 16 + l16] = f2bf(sc[m][nt][r]);

        bf16x8_t aS[2][2];
#pragma unroll
        for (int m = 0; m < 2; ++m)
#pragma unroll
            for (int kp2 = 0; kp2 < 2; ++kp2)
                aS[m][kp2] = *(const bf16x8_t*)&Ss[(m * 16 + l16) * STR + kp2 * 32 + quad * 8];

        // ---- O += S V on current V buffer ----
#pragma unroll
        for (int kp2 = 0; kp2 < 2; ++kp2)
#pragma unroll
            for (int m = 0; m < 2; ++m)
#pragma unroll
                for (int nd = 0; nd < 4; ++nd)
                    acc[m][nd] = __builtin_amdgcn_mfma_f32_16x16x32_bf16(
                        aS[m][kp2], bV[cur][nd][kp2], acc[m][nd], 0, 0, 0);

        cur ^= 1;
    }

    // ---- diagonal tile (in bK[cur]/bV[cur]): causal mask ----
    {
        int ntv = odd ? 4 : 2;
        int kpv = odd ? 2 : 1;

        f32x4_t sc[2][4];
#pragma unroll
        for (int m = 0; m < 2; ++m)
#pragma unroll
            for (int nt = 0; nt < 4; ++nt) sc[m][nt] = (f32x4_t){0.f, 0.f, 0.f, 0.f};
#pragma unroll
        for (int kk = 0; kk < 2; ++kk)
#pragma unroll
            for (int m = 0; m < 2; ++m)
#pragma unroll
                for (int nt = 0; nt < 4; ++nt)
                    if (nt < ntv)
                        sc[m][nt] = __builtin_amdgcn_mfma_f32_16x16x32_bf16(
                            aQ[m][kk], bK[cur][nt][kk], sc[m][nt], 0, 0, 0);

        // keep iff global row >= global col; q0 - ktmax*64 = odd*32
#pragma unroll
        for (int m = 0; m < 2; ++m)
#pragma unroll
            for (int nt = 0; nt < 4; ++nt) {
                if (nt >= ntv) continue;
                int dlt = (odd * 2 + m - nt) * 16;
#pragma unroll
                for (int r = 0; r < 4; ++r) {
                    int rr = quad * 4 + r;
                    float v = ((rr + dlt) >= l16) ? sc[m][nt][r] : 0.0f;
                    Ss[(m * 16 + rr) * STR + nt * 16 + l16] = f2bf(v);
                }
            }

        bf16x8_t aS[2][2];
#pragma unroll
        for (int m = 0; m < 2; ++m)
#pragma unroll
            for (int kp2 = 0; kp2 < 2; ++kp2)
                if (kp2 < kpv)
                    aS[m][kp2] =
                        *(const bf16x8_t*)&Ss[(m * 16 + l16) * STR + kp2 * 32 + quad * 8];

#pragma unroll
        for (int kp2 = 0; kp2 < 2; ++kp2)
#pragma unroll
            for (int m = 0; m < 2; ++m)
#pragma unroll
                for (int nd = 0; nd < 4; ++nd)
                    if (kp2 < kpv)
                        acc[m][nd] = __builtin_amdgcn_mfma_f32_16x16x32_bf16(
                            aS[m][kp2], bV[cur][nd][kp2], acc[m][nd], 0, 0, 0);
    }

    // ---- epilogue ----
#pragma unroll
    for (int m = 0; m < 2; ++m)
#pragma unroll
        for (int nd = 0; nd < 4; ++nd)
#pragma unroll
            for (int r = 0; r < 4; ++r) {
                int row = q0 + m * 16 + quad * 4 + r;
                out[((long)(b * S_ + row)) * 1024 + hh * 64 + nd * 16 + l16] = acc[m][nd][r];
            }
}

extern "C" void kernel_launch(void* const* d_in, const int* in_sizes, int n_in,
                              void* d_out, int out_size, void* d_ws, size_t ws_size,
                              hipStream_t stream) {
    const float* Q = (const float*)d_in[0];
    const float* K = (const float*)d_in[1];
    const float* V = (const float*)d_in[2];
    float* out = (float*)d_out;

    const size_t perBuf = (size_t)B_ * H_ * S_ * D_;
    unsigned short* qb = (unsigned short*)d_ws;
    unsigned short* kb = qb + perBuf;
    unsigned short* vt = kb + perBuf;

    hipLaunchKernelGGL(prep_kernel, dim3(512), dim3(256), 0, stream, Q, K, V, qb, kb, vt);
    hipLaunchKernelGGL(retention_kernel, dim3(2048), dim3(64), 0, stream, qb, kb, vt, out);
}

// Round 4
// 145.435 us; speedup vs baseline: 1.9841x; 1.9841x over previous
//
#include <hip/hip_runtime.h>
#include <hip/hip_bf16.h>
#include <math.h>

#define B_  2
#define S_  2048
#define H_  16
#define D_  64
#define STR 72   // padded LDS row stride for the score transform (shorts)

typedef __attribute__((ext_vector_type(8))) short bf16x8_t;
typedef __attribute__((ext_vector_type(4))) float f32x4_t;

__device__ __forceinline__ unsigned short f2bf(float f) {
    __hip_bfloat16 h = __float2bfloat16(f);
    return __builtin_bit_cast(unsigned short, h);
}

// async global->LDS, 16B per lane; LDS dest = wave-uniform base + lane*16
__device__ __forceinline__ void async16(const unsigned short* g, unsigned short* l) {
    __builtin_amdgcn_global_load_lds(
        (const __attribute__((address_space(1))) unsigned int*)g,
        (__attribute__((address_space(3))) unsigned int*)l, 16, 0, 0);
}

#define WAITV4 asm volatile("s_waitcnt vmcnt(4)" ::: "memory")
#define WAITV0 asm volatile("s_waitcnt vmcnt(0)" ::: "memory")
#define BAR    asm volatile("s_barrier" ::: "memory")

// ---------------- kernel 1: fused prep (unchanged from R3; correctness-proven) ----------
__global__ __launch_bounds__(256) void prep_kernel(const float* __restrict__ Q,
                                                   const float* __restrict__ K,
                                                   const float* __restrict__ V,
                                                   unsigned short* __restrict__ qb,
                                                   unsigned short* __restrict__ kb,
                                                   unsigned short* __restrict__ vt) {
    __shared__ float tile[64 * 65];
    int t   = threadIdx.x;
    int bh  = blockIdx.x >> 4;
    int scn = blockIdx.x & 15;
    int b = bh >> 4, hh = bh & 15;
    int s0 = scn * 128;

    float lnv   = -3.4657359027997265f + (float)hh * (-0.18483924814931874f);
    float gamma = 1.0f - expf(lnv);
    float l2g   = log2f(gamma);

#pragma unroll
    for (int it = 0; it < 16; ++it) {
        int idx = it * 256 + t;
        int i  = idx & 31;
        int sl = idx >> 5;
        int s  = s0 + sl;
        float pos = (float)s;

        float bsc  = (2.0f * (float)i + 25.6f) / 89.6f;
        float xsc  = exp2f(log2f(bsc) * pos * (1.0f / 512.0f));
        float invf = exp2f(-(float)i * (13.287712379549449f / 32.0f));
        float ang  = pos * invf;
        float kq = rintf(ang * 0.15915494309189535f);
        float r  = fmaf(kq, -6.2831853071795865f, ang);
        float sn = sinf(r), cs = cosf(r);

        float gs  = exp2f(pos * l2g);
        float gsi = exp2f(-pos * l2g);
        float rxs = 1.0f / xsc;

        float cq = cs * xsc * gs,  sq = sn * xsc * gs;
        float ck = cs * rxs * gsi, sk = sn * rxs * gsi;

        long inIdx = ((long)(b * S_ + s)) * 1024 + hh * 64 + 2 * i;
        float2 xq = *(const float2*)(Q + inIdx);
        float2 xk = *(const float2*)(K + inIdx);
        float q0 = xq.x * cq - xq.y * sq, q1 = xq.y * cq + xq.x * sq;
        float k0 = xk.x * ck - xk.y * sk, k1 = xk.y * ck + xk.x * sk;

        long outIdx = ((long)(bh * S_ + s)) * 64 + 2 * i;
        *(unsigned int*)(qb + outIdx) = (unsigned)f2bf(q0) | ((unsigned)f2bf(q1) << 16);
        *(unsigned int*)(kb + outIdx) = (unsigned)f2bf(k0) | ((unsigned)f2bf(k1) << 16);
    }

#pragma unroll
    for (int half = 0; half < 2; ++half) {
        __syncthreads();
        int sb = s0 + half * 64;
#pragma unroll
        for (int it = 0; it < 4; ++it) {
            int f  = it * 256 + t;
            int sl = f >> 4;
            int d4 = f & 15;
            float4 v = *(const float4*)(V + ((long)(b * S_ + sb + sl)) * 1024 + hh * 64 + d4 * 4);
            tile[sl * 65 + d4 * 4 + 0] = v.x;
            tile[sl * 65 + d4 * 4 + 1] = v.y;
            tile[sl * 65 + d4 * 4 + 2] = v.z;
            tile[sl * 65 + d4 * 4 + 3] = v.w;
        }
        __syncthreads();
        int d = t >> 2, c = t & 3;
        unsigned int pk[8];
#pragma unroll
        for (int jj = 0; jj < 8; ++jj) {
            float f0 = tile[(c * 16 + 2 * jj + 0) * 65 + d];
            float f1 = tile[(c * 16 + 2 * jj + 1) * 65 + d];
            pk[jj] = (unsigned int)f2bf(f0) | ((unsigned int)f2bf(f1) << 16);
        }
        unsigned short* outp = vt + ((long)(bh * 64 + d)) * S_ + sb + c * 16;
        ((uint4*)outp)[0] = make_uint4(pk[0], pk[1], pk[2], pk[3]);
        ((uint4*)outp)[1] = make_uint4(pk[4], pk[5], pk[6], pk[7]);
    }
}

// ---------------- kernel 2: retention, async-LDS pipelined ----------------
// 512 blocks x 256 threads. Block = (b,h) x 128 q-rows; wave w owns rows w*32..+32.
// K/V 64x64 tiles double-buffered in LDS via global_load_lds (XOR-swizzled 16B blocks).
// Raw s_barrier + manual vmcnt(4): prefetch stays in flight across the barrier.
// NOTE (R3 lesson): no runtime-indexed local arrays anywhere -> no scratch spills.
__global__ __launch_bounds__(256, 2) void retention_kernel(const unsigned short* __restrict__ qb,
                                                           const unsigned short* __restrict__ kb,
                                                           const unsigned short* __restrict__ vt,
                                                           float* __restrict__ out) {
    __shared__ __align__(16) unsigned short K0[4096], K1[4096];   // 8 KB each
    __shared__ __align__(16) unsigned short V0[4096], V1[4096];
    __shared__ __align__(16) unsigned short Ss[4][32 * STR];      // 4.5 KB/wave

    int t = threadIdx.x;
    int w = t >> 6, lane = t & 63, quad = lane >> 4, l16 = lane & 15;

    // balance map: blocks i and i+256 have complementary KV lengths (sum = 34 tiles)
    int i = blockIdx.x;
    int bh, g;
    if (i < 256) { bh = i >> 4;        g = i & 15; }
    else         { bh = 16 + ((i - 256) >> 4); g = 15 - (i & 15); }
    int b = bh >> 4, hh = bh & 15;

    int q0w  = g * 128 + w * 32;        // wave's first q-row
    int dkt  = 2 * g + (w >> 1);        // wave's diagonal KV tile
    int odd  = w & 1;                   // row offset within diagonal tile = odd*32
    int kvend = 2 * g + 2;              // KV tiles this block walks (always even)

    const unsigned short* qB = qb + ((long)bh * S_ + q0w) * 64;
    const unsigned short* kB = kb + (long)bh * S_ * 64;
    const unsigned short* vB = vt + (long)bh * 64 * S_;

    // Q A-fragments in registers for the whole kernel
    bf16x8_t aQ[2][2];
#pragma unroll
    for (int m = 0; m < 2; ++m)
#pragma unroll
        for (int kk = 0; kk < 2; ++kk)
            aQ[m][kk] = *(const bf16x8_t*)(qB + (m * 16 + l16) * 64 + kk * 32 + quad * 8);

    f32x4_t acc[2][4];
#pragma unroll
    for (int m = 0; m < 2; ++m)
#pragma unroll
        for (int nd = 0; nd < 4; ++nd) acc[m][nd] = (f32x4_t){0.f, 0.f, 0.f, 0.f};

    // stage one K+V tile: wave w issues 4 DMA instrs (2 K + 2 V), 1 KB each.
    // LDS 16B-block (row, c) stored at index row*8 + (c ^ (row&7))  [bank swizzle]
    auto stage = [&](unsigned short* Kd, unsigned short* Vd, int kt) {
        const unsigned short* kSrc = kB + kt * 4096;
        const unsigned short* vSrc = vB + kt * 64;
#pragma unroll
        for (int ii = 0; ii < 2; ++ii) {
            int ins = w * 2 + ii;                 // 0..7 across the block
            int row = ins * 8 + (lane >> 3);
            int c   = (lane & 7) ^ (row & 7);
            async16(kSrc + row * 64 + c * 8, Kd + ins * 512);
            async16(vSrc + (long)row * S_ + c * 8, Vd + ins * 512);
        }
    };

    auto compute = [&](const unsigned short* Kt, const unsigned short* Vt, int kt) {
        f32x4_t sc[2][4];
#pragma unroll
        for (int m = 0; m < 2; ++m)
#pragma unroll
            for (int nt = 0; nt < 4; ++nt) sc[m][nt] = (f32x4_t){0.f, 0.f, 0.f, 0.f};

#pragma unroll
        for (int kk = 0; kk < 2; ++kk)
#pragma unroll
            for (int nt = 0; nt < 4; ++nt) {
                int krow = nt * 16 + l16;
                bf16x8_t bk = *(const bf16x8_t*)&Kt[krow * 64 +
                                                   (((kk * 4 + quad) ^ (krow & 7)) * 8)];
                sc[0][nt] = __builtin_amdgcn_mfma_f32_16x16x32_bf16(aQ[0][kk], bk, sc[0][nt], 0, 0, 0);
                sc[1][nt] = __builtin_amdgcn_mfma_f32_16x16x32_bf16(aQ[1][kk], bk, sc[1][nt], 0, 0, 0);
            }

        unsigned short* ssw = Ss[w];
        if (kt < dkt) {
#pragma unroll
            for (int m = 0; m < 2; ++m)
#pragma unroll
                for (int nt = 0; nt < 4; ++nt)
#pragma unroll
                    for (int r = 0; r < 4; ++r)
                        ssw[(m * 16 + quad * 4 + r) * STR + nt * 16 + l16] = f2bf(sc[m][nt][r]);
        } else {  // diagonal tile: causal mask (also zeroes the out-of-range cols)
#pragma unroll
            for (int m = 0; m < 2; ++m)
#pragma unroll
                for (int nt = 0; nt < 4; ++nt) {
                    int dlt = odd * 32 + (m - nt) * 16;
#pragma unroll
                    for (int r = 0; r < 4; ++r) {
                        int rr = quad * 4 + r;
                        float v = ((rr + dlt) >= l16) ? sc[m][nt][r] : 0.0f;
                        ssw[(m * 16 + rr) * STR + nt * 16 + l16] = f2bf(v);
                    }
                }
        }

        bf16x8_t aS[2][2];
#pragma unroll
        for (int m = 0; m < 2; ++m)
#pragma unroll
            for (int kp2 = 0; kp2 < 2; ++kp2)
                aS[m][kp2] = *(const bf16x8_t*)&ssw[(m * 16 + l16) * STR + kp2 * 32 + quad * 8];

#pragma unroll
        for (int kp2 = 0; kp2 < 2; ++kp2)
#pragma unroll
            for (int nd = 0; nd < 4; ++nd) {
                int vrow = nd * 16 + l16;
                bf16x8_t bv = *(const bf16x8_t*)&Vt[vrow * 64 +
                                                   (((kp2 * 4 + quad) ^ (vrow & 7)) * 8)];
                acc[0][nd] = __builtin_amdgcn_mfma_f32_16x16x32_bf16(aS[0][kp2], bv, acc[0][nd], 0, 0, 0);
                acc[1][nd] = __builtin_amdgcn_mfma_f32_16x16x32_bf16(aS[1][kp2], bv, acc[1][nd], 0, 0, 0);
            }
    };

    // ---- pipelined main loop (kvend is even; static buffer names, unroll by 2) ----
    stage(K0, V0, 0);
    for (int kt = 0; kt < kvend; kt += 2) {
        // step A: compute kt from buf0, prefetch kt+1 into buf1 (kt+1 < kvend always)
        stage(K1, V1, kt + 1);
        WAITV4;                       // own tile-kt DMAs done; kt+1 stays in flight
        BAR;                          // everyone's tile-kt DMAs done
        if (kt <= dkt) compute(K0, V0, kt);
        BAR;                          // all waves done reading buf0

        // step B: compute kt+1 from buf1, prefetch kt+2 into buf0
        if (kt + 2 < kvend) { stage(K0, V0, kt + 2); WAITV4; }
        else                { WAITV0; }
        BAR;
        if (kt + 1 <= dkt) compute(K1, V1, kt + 1);
        BAR;
    }

    // ---- epilogue: C layout row=quad*4+r, col=l16 ----
#pragma unroll
    for (int m = 0; m < 2; ++m)
#pragma unroll
        for (int nd = 0; nd < 4; ++nd)
#pragma unroll
            for (int r = 0; r < 4; ++r) {
                int row = q0w + m * 16 + quad * 4 + r;
                out[((long)(b * S_ + row)) * 1024 + hh * 64 + nd * 16 + l16] = acc[m][nd][r];
            }
}

extern "C" void kernel_launch(void* const* d_in, const int* in_sizes, int n_in,
                              void* d_out, int out_size, void* d_ws, size_t ws_size,
                              hipStream_t stream) {
    const float* Q = (const float*)d_in[0];
    const float* K = (const float*)d_in[1];
    const float* V = (const float*)d_in[2];
    float* out = (float*)d_out;

    const size_t perBuf = (size_t)B_ * H_ * S_ * D_;
    unsigned short* qb = (unsigned short*)d_ws;
    unsigned short* kb = qb + perBuf;
    unsigned short* vt = kb + perBuf;

    hipLaunchKernelGGL(prep_kernel, dim3(512), dim3(256), 0, stream, Q, K, V, qb, kb, vt);
    hipLaunchKernelGGL(retention_kernel, dim3(512), dim3(256), 0, stream, qb, kb, vt, out);
}

// Round 5
// 139.254 us; speedup vs baseline: 2.0722x; 1.0444x over previous
//
#include <hip/hip_runtime.h>
#include <hip/hip_bf16.h>
#include <math.h>

#define B_  2
#define S_  2048
#define H_  16
#define D_  64
#define STR 72   // padded LDS row stride for the score transform (shorts)

typedef __attribute__((ext_vector_type(8))) short bf16x8_t;
typedef __attribute__((ext_vector_type(4))) float f32x4_t;

__device__ __forceinline__ unsigned short f2bf(float f) {
    __hip_bfloat16 h = __float2bfloat16(f);
    return __builtin_bit_cast(unsigned short, h);
}

// async global->LDS, 16B per lane; LDS dest = wave-uniform base + lane*16
__device__ __forceinline__ void async16(const unsigned short* g, unsigned short* l) {
    __builtin_amdgcn_global_load_lds(
        (const __attribute__((address_space(1))) unsigned int*)g,
        (__attribute__((address_space(3))) unsigned int*)l, 16, 0, 0);
}

#define WAITV4 asm volatile("s_waitcnt vmcnt(4)" ::: "memory")
#define WAITV0 asm volatile("s_waitcnt vmcnt(0)" ::: "memory")
#define BAR    asm volatile("s_barrier" ::: "memory")

// ---------------- kernel 1: fused prep (unchanged; correctness-proven) ----------
__global__ __launch_bounds__(256) void prep_kernel(const float* __restrict__ Q,
                                                   const float* __restrict__ K,
                                                   const float* __restrict__ V,
                                                   unsigned short* __restrict__ qb,
                                                   unsigned short* __restrict__ kb,
                                                   unsigned short* __restrict__ vt) {
    __shared__ float tile[64 * 65];
    int t   = threadIdx.x;
    int bh  = blockIdx.x >> 4;
    int scn = blockIdx.x & 15;
    int b = bh >> 4, hh = bh & 15;
    int s0 = scn * 128;

    float lnv   = -3.4657359027997265f + (float)hh * (-0.18483924814931874f);
    float gamma = 1.0f - expf(lnv);
    float l2g   = log2f(gamma);

#pragma unroll
    for (int it = 0; it < 16; ++it) {
        int idx = it * 256 + t;
        int i  = idx & 31;
        int sl = idx >> 5;
        int s  = s0 + sl;
        float pos = (float)s;

        float bsc  = (2.0f * (float)i + 25.6f) / 89.6f;
        float xsc  = exp2f(log2f(bsc) * pos * (1.0f / 512.0f));
        float invf = exp2f(-(float)i * (13.287712379549449f / 32.0f));
        float ang  = pos * invf;
        float kq = rintf(ang * 0.15915494309189535f);
        float r  = fmaf(kq, -6.2831853071795865f, ang);
        float sn = sinf(r), cs = cosf(r);

        float gs  = exp2f(pos * l2g);
        float gsi = exp2f(-pos * l2g);
        float rxs = 1.0f / xsc;

        float cq = cs * xsc * gs,  sq = sn * xsc * gs;
        float ck = cs * rxs * gsi, sk = sn * rxs * gsi;

        long inIdx = ((long)(b * S_ + s)) * 1024 + hh * 64 + 2 * i;
        float2 xq = *(const float2*)(Q + inIdx);
        float2 xk = *(const float2*)(K + inIdx);
        float q0 = xq.x * cq - xq.y * sq, q1 = xq.y * cq + xq.x * sq;
        float k0 = xk.x * ck - xk.y * sk, k1 = xk.y * ck + xk.x * sk;

        long outIdx = ((long)(bh * S_ + s)) * 64 + 2 * i;
        *(unsigned int*)(qb + outIdx) = (unsigned)f2bf(q0) | ((unsigned)f2bf(q1) << 16);
        *(unsigned int*)(kb + outIdx) = (unsigned)f2bf(k0) | ((unsigned)f2bf(k1) << 16);
    }

#pragma unroll
    for (int half = 0; half < 2; ++half) {
        __syncthreads();
        int sb = s0 + half * 64;
#pragma unroll
        for (int it = 0; it < 4; ++it) {
            int f  = it * 256 + t;
            int sl = f >> 4;
            int d4 = f & 15;
            float4 v = *(const float4*)(V + ((long)(b * S_ + sb + sl)) * 1024 + hh * 64 + d4 * 4);
            tile[sl * 65 + d4 * 4 + 0] = v.x;
            tile[sl * 65 + d4 * 4 + 1] = v.y;
            tile[sl * 65 + d4 * 4 + 2] = v.z;
            tile[sl * 65 + d4 * 4 + 3] = v.w;
        }
        __syncthreads();
        int d = t >> 2, c = t & 3;
        unsigned int pk[8];
#pragma unroll
        for (int jj = 0; jj < 8; ++jj) {
            float f0 = tile[(c * 16 + 2 * jj + 0) * 65 + d];
            float f1 = tile[(c * 16 + 2 * jj + 1) * 65 + d];
            pk[jj] = (unsigned int)f2bf(f0) | ((unsigned int)f2bf(f1) << 16);
        }
        unsigned short* outp = vt + ((long)(bh * 64 + d)) * S_ + sb + c * 16;
        ((uint4*)outp)[0] = make_uint4(pk[0], pk[1], pk[2], pk[3]);
        ((uint4*)outp)[1] = make_uint4(pk[4], pk[5], pk[6], pk[7]);
    }
}

// ---------------- kernel 2: retention, async-LDS pipelined, LONGEST-FIRST ----------------
// R4 structure unchanged except the blockIdx -> (bh, g) map: g descends with blockIdx
// so the 32-stage blocks (g=15) dispatch first and short blocks backfill -> no tail.
__global__ __launch_bounds__(256, 2) void retention_kernel(const unsigned short* __restrict__ qb,
                                                           const unsigned short* __restrict__ kb,
                                                           const unsigned short* __restrict__ vt,
                                                           float* __restrict__ out) {
    __shared__ __align__(16) unsigned short K0[4096], K1[4096];   // 8 KB each
    __shared__ __align__(16) unsigned short V0[4096], V1[4096];
    __shared__ __align__(16) unsigned short Ss[4][32 * STR];      // 4.5 KB/wave

    int t = threadIdx.x;
    int w = t >> 6, lane = t & 63, quad = lane >> 4, l16 = lane & 15;

    // longest-first: blocks 0..31 are g=15 (32 stages), ..., blocks 480..511 are g=0
    int i  = blockIdx.x;
    int g  = 15 - (i >> 5);
    int bh = i & 31;
    int b = bh >> 4, hh = bh & 15;

    int q0w  = g * 128 + w * 32;        // wave's first q-row
    int dkt  = 2 * g + (w >> 1);        // wave's diagonal KV tile
    int odd  = w & 1;                   // row offset within diagonal tile = odd*32
    int kvend = 2 * g + 2;              // KV tiles this block walks (even)

    const unsigned short* qB = qb + ((long)bh * S_ + q0w) * 64;
    const unsigned short* kB = kb + (long)bh * S_ * 64;
    const unsigned short* vB = vt + (long)bh * 64 * S_;

    bf16x8_t aQ[2][2];
#pragma unroll
    for (int m = 0; m < 2; ++m)
#pragma unroll
        for (int kk = 0; kk < 2; ++kk)
            aQ[m][kk] = *(const bf16x8_t*)(qB + (m * 16 + l16) * 64 + kk * 32 + quad * 8);

    f32x4_t acc[2][4];
#pragma unroll
    for (int m = 0; m < 2; ++m)
#pragma unroll
        for (int nd = 0; nd < 4; ++nd) acc[m][nd] = (f32x4_t){0.f, 0.f, 0.f, 0.f};

    // stage one K+V tile: wave w issues 4 DMA instrs (2 K + 2 V), 1 KB each.
    // LDS 16B-block (row, c) stored at slot c ^ (row&7)  [bank swizzle]
    auto stage = [&](unsigned short* Kd, unsigned short* Vd, int kt) {
        const unsigned short* kSrc = kB + kt * 4096;
        const unsigned short* vSrc = vB + kt * 64;
#pragma unroll
        for (int ii = 0; ii < 2; ++ii) {
            int ins = w * 2 + ii;                 // 0..7 across the block
            int row = ins * 8 + (lane >> 3);
            int c   = (lane & 7) ^ (row & 7);
            async16(kSrc + row * 64 + c * 8, Kd + ins * 512);
            async16(vSrc + (long)row * S_ + c * 8, Vd + ins * 512);
        }
    };

    auto compute = [&](const unsigned short* Kt, const unsigned short* Vt, int kt) {
        f32x4_t sc[2][4];
#pragma unroll
        for (int m = 0; m < 2; ++m)
#pragma unroll
            for (int nt = 0; nt < 4; ++nt) sc[m][nt] = (f32x4_t){0.f, 0.f, 0.f, 0.f};

#pragma unroll
        for (int kk = 0; kk < 2; ++kk)
#pragma unroll
            for (int nt = 0; nt < 4; ++nt) {
                int krow = nt * 16 + l16;
                bf16x8_t bk = *(const bf16x8_t*)&Kt[krow * 64 +
                                                   (((kk * 4 + quad) ^ (krow & 7)) * 8)];
                sc[0][nt] = __builtin_amdgcn_mfma_f32_16x16x32_bf16(aQ[0][kk], bk, sc[0][nt], 0, 0, 0);
                sc[1][nt] = __builtin_amdgcn_mfma_f32_16x16x32_bf16(aQ[1][kk], bk, sc[1][nt], 0, 0, 0);
            }

        unsigned short* ssw = Ss[w];
        if (kt < dkt) {
#pragma unroll
            for (int m = 0; m < 2; ++m)
#pragma unroll
                for (int nt = 0; nt < 4; ++nt)
#pragma unroll
                    for (int r = 0; r < 4; ++r)
                        ssw[(m * 16 + quad * 4 + r) * STR + nt * 16 + l16] = f2bf(sc[m][nt][r]);
        } else {  // diagonal tile: causal mask (also zeroes out-of-range cols)
#pragma unroll
            for (int m = 0; m < 2; ++m)
#pragma unroll
                for (int nt = 0; nt < 4; ++nt) {
                    int dlt = odd * 32 + (m - nt) * 16;
#pragma unroll
                    for (int r = 0; r < 4; ++r) {
                        int rr = quad * 4 + r;
                        float v = ((rr + dlt) >= l16) ? sc[m][nt][r] : 0.0f;
                        ssw[(m * 16 + rr) * STR + nt * 16 + l16] = f2bf(v);
                    }
                }
        }

        bf16x8_t aS[2][2];
#pragma unroll
        for (int m = 0; m < 2; ++m)
#pragma unroll
            for (int kp2 = 0; kp2 < 2; ++kp2)
                aS[m][kp2] = *(const bf16x8_t*)&ssw[(m * 16 + l16) * STR + kp2 * 32 + quad * 8];

#pragma unroll
        for (int kp2 = 0; kp2 < 2; ++kp2)
#pragma unroll
            for (int nd = 0; nd < 4; ++nd) {
                int vrow = nd * 16 + l16;
                bf16x8_t bv = *(const bf16x8_t*)&Vt[vrow * 64 +
                                                   (((kp2 * 4 + quad) ^ (vrow & 7)) * 8)];
                acc[0][nd] = __builtin_amdgcn_mfma_f32_16x16x32_bf16(aS[0][kp2], bv, acc[0][nd], 0, 0, 0);
                acc[1][nd] = __builtin_amdgcn_mfma_f32_16x16x32_bf16(aS[1][kp2], bv, acc[1][nd], 0, 0, 0);
            }
    };

    // ---- pipelined main loop (kvend even; static buffer names, unroll by 2) ----
    stage(K0, V0, 0);
    for (int kt = 0; kt < kvend; kt += 2) {
        stage(K1, V1, kt + 1);
        WAITV4;                       // own tile-kt DMAs done; kt+1 stays in flight
        BAR;                          // everyone's tile-kt DMAs done
        if (kt <= dkt) compute(K0, V0, kt);
        BAR;                          // all waves done reading buf0

        if (kt + 2 < kvend) { stage(K0, V0, kt + 2); WAITV4; }
        else                { WAITV0; }
        BAR;
        if (kt + 1 <= dkt) compute(K1, V1, kt + 1);
        BAR;
    }

    // ---- epilogue: C layout row=quad*4+r, col=l16 ----
#pragma unroll
    for (int m = 0; m < 2; ++m)
#pragma unroll
        for (int nd = 0; nd < 4; ++nd)
#pragma unroll
            for (int r = 0; r < 4; ++r) {
                int row = q0w + m * 16 + quad * 4 + r;
                out[((long)(b * S_ + row)) * 1024 + hh * 64 + nd * 16 + l16] = acc[m][nd][r];
            }
}

extern "C" void kernel_launch(void* const* d_in, const int* in_sizes, int n_in,
                              void* d_out, int out_size, void* d_ws, size_t ws_size,
                              hipStream_t stream) {
    const float* Q = (const float*)d_in[0];
    const float* K = (const float*)d_in[1];
    const float* V = (const float*)d_in[2];
    float* out = (float*)d_out;

    const size_t perBuf = (size_t)B_ * H_ * S_ * D_;
    unsigned short* qb = (unsigned short*)d_ws;
    unsigned short* kb = qb + perBuf;
    unsigned short* vt = kb + perBuf;

    hipLaunchKernelGGL(prep_kernel, dim3(512), dim3(256), 0, stream, Q, K, V, qb, kb, vt);
    hipLaunchKernelGGL(retention_kernel, dim3(512), dim3(256), 0, stream, qb, kb, vt, out);
}

// Round 6
// 134.178 us; speedup vs baseline: 2.1506x; 1.0378x over previous
//
#include <hip/hip_runtime.h>
#include <hip/hip_bf16.h>
#include <math.h>

#define B_  2
#define S_  2048
#define H_  16
#define D_  64
#define SST 40   // score-strip stride (shorts): 80 B rows, 16B-aligned

typedef __attribute__((ext_vector_type(8))) short bf16x8_t;
typedef __attribute__((ext_vector_type(4))) float f32x4_t;

__device__ __forceinline__ unsigned short f2bf(float f) {
    __hip_bfloat16 h = __float2bfloat16(f);
    return __builtin_bit_cast(unsigned short, h);
}

// async global->LDS, 16B per lane; LDS dest = wave-uniform base + lane*16
__device__ __forceinline__ void async16(const unsigned short* g, unsigned short* l) {
    __builtin_amdgcn_global_load_lds(
        (const __attribute__((address_space(1))) unsigned int*)g,
        (__attribute__((address_space(3))) unsigned int*)l, 16, 0, 0);
}

#define WAITV2 asm volatile("s_waitcnt vmcnt(2)" ::: "memory")
#define WAITV0 asm volatile("s_waitcnt vmcnt(0)" ::: "memory")
#define BAR    asm volatile("s_barrier" ::: "memory")

// ---------------- kernel 1: fused prep (unchanged; correctness-proven) ----------
__global__ __launch_bounds__(256) void prep_kernel(const float* __restrict__ Q,
                                                   const float* __restrict__ K,
                                                   const float* __restrict__ V,
                                                   unsigned short* __restrict__ qb,
                                                   unsigned short* __restrict__ kb,
                                                   unsigned short* __restrict__ vt) {
    __shared__ float tile[64 * 65];
    int t   = threadIdx.x;
    int bh  = blockIdx.x >> 4;
    int scn = blockIdx.x & 15;
    int b = bh >> 4, hh = bh & 15;
    int s0 = scn * 128;

    float lnv   = -3.4657359027997265f + (float)hh * (-0.18483924814931874f);
    float gamma = 1.0f - expf(lnv);
    float l2g   = log2f(gamma);

#pragma unroll
    for (int it = 0; it < 16; ++it) {
        int idx = it * 256 + t;
        int i  = idx & 31;
        int sl = idx >> 5;
        int s  = s0 + sl;
        float pos = (float)s;

        float bsc  = (2.0f * (float)i + 25.6f) / 89.6f;
        float xsc  = exp2f(log2f(bsc) * pos * (1.0f / 512.0f));
        float invf = exp2f(-(float)i * (13.287712379549449f / 32.0f));
        float ang  = pos * invf;
        float kq = rintf(ang * 0.15915494309189535f);
        float r  = fmaf(kq, -6.2831853071795865f, ang);
        float sn = sinf(r), cs = cosf(r);

        float gs  = exp2f(pos * l2g);
        float gsi = exp2f(-pos * l2g);
        float rxs = 1.0f / xsc;

        float cq = cs * xsc * gs,  sq = sn * xsc * gs;
        float ck = cs * rxs * gsi, sk = sn * rxs * gsi;

        long inIdx = ((long)(b * S_ + s)) * 1024 + hh * 64 + 2 * i;
        float2 xq = *(const float2*)(Q + inIdx);
        float2 xk = *(const float2*)(K + inIdx);
        float q0 = xq.x * cq - xq.y * sq, q1 = xq.y * cq + xq.x * sq;
        float k0 = xk.x * ck - xk.y * sk, k1 = xk.y * ck + xk.x * sk;

        long outIdx = ((long)(bh * S_ + s)) * 64 + 2 * i;
        *(unsigned int*)(qb + outIdx) = (unsigned)f2bf(q0) | ((unsigned)f2bf(q1) << 16);
        *(unsigned int*)(kb + outIdx) = (unsigned)f2bf(k0) | ((unsigned)f2bf(k1) << 16);
    }

#pragma unroll
    for (int half = 0; half < 2; ++half) {
        __syncthreads();
        int sb = s0 + half * 64;
#pragma unroll
        for (int it = 0; it < 4; ++it) {
            int f  = it * 256 + t;
            int sl = f >> 4;
            int d4 = f & 15;
            float4 v = *(const float4*)(V + ((long)(b * S_ + sb + sl)) * 1024 + hh * 64 + d4 * 4);
            tile[sl * 65 + d4 * 4 + 0] = v.x;
            tile[sl * 65 + d4 * 4 + 1] = v.y;
            tile[sl * 65 + d4 * 4 + 2] = v.z;
            tile[sl * 65 + d4 * 4 + 3] = v.w;
        }
        __syncthreads();
        int d = t >> 2, c = t & 3;
        unsigned int pk[8];
#pragma unroll
        for (int jj = 0; jj < 8; ++jj) {
            float f0 = tile[(c * 16 + 2 * jj + 0) * 65 + d];
            float f1 = tile[(c * 16 + 2 * jj + 1) * 65 + d];
            pk[jj] = (unsigned int)f2bf(f0) | ((unsigned int)f2bf(f1) << 16);
        }
        unsigned short* outp = vt + ((long)(bh * 64 + d)) * S_ + sb + c * 16;
        ((uint4*)outp)[0] = make_uint4(pk[0], pk[1], pk[2], pk[3]);
        ((uint4*)outp)[1] = make_uint4(pk[4], pk[5], pk[6], pk[7]);
    }
}

// ---------------- kernel 2: retention, kv-half wave-split (8 waves/block) ----------------
// 512 blocks x 512 threads. Wave (qw,p): qw = 32 q-rows, p = kv-half of every tile.
// All 8 waves active each phase; score strips wave-private; partial-O reduced at end.
// VGPR capped at 128 by __launch_bounds__(512,4) -> 2 blocks/CU = 4 waves/SIMD.
__global__ __launch_bounds__(512, 4) void retention_kernel(const unsigned short* __restrict__ qb,
                                                           const unsigned short* __restrict__ kb,
                                                           const unsigned short* __restrict__ vt,
                                                           float* __restrict__ out) {
    __shared__ __align__(16) unsigned short KV[16384];        // [K0|V0|K1|V1], 4096 shorts each
    __shared__ __align__(16) unsigned short Ss[8][32 * SST];  // wave-private score strips
    unsigned short* K0 = KV;
    unsigned short* V0 = KV + 4096;
    unsigned short* K1 = KV + 8192;
    unsigned short* V1 = KV + 12288;

    int t = threadIdx.x;
    int w = t >> 6, lane = t & 63, quad = lane >> 4, l16 = lane & 15;
    int qw = w & 3;          // q-subtile (32 rows)
    int p  = w >> 2;         // kv-half (0: cols 0..31, 1: cols 32..63)

    // longest-first dispatch
    int i  = blockIdx.x;
    int g  = 15 - (i >> 5);
    int bh = i & 31;
    int b = bh >> 4, hh = bh & 15;

    int q0w  = g * 128 + qw * 32;
    int dkt  = 2 * g + (qw >> 1);     // wave's diagonal KV tile
    int odd  = qw & 1;                // row offset within diagonal tile = odd*32
    int kvend = 2 * g + 2;            // tiles this block walks (even)

    const unsigned short* qB = qb + ((long)bh * S_ + q0w) * 64;
    const unsigned short* kB = kb + (long)bh * S_ * 64;
    const unsigned short* vB = vt + (long)bh * 64 * S_;

    bf16x8_t aQ[2][2];
#pragma unroll
    for (int m = 0; m < 2; ++m)
#pragma unroll
        for (int kk = 0; kk < 2; ++kk)
            aQ[m][kk] = *(const bf16x8_t*)(qB + (m * 16 + l16) * 64 + kk * 32 + quad * 8);

    f32x4_t acc[2][4];   // partial O over this wave's kv-half
#pragma unroll
    for (int m = 0; m < 2; ++m)
#pragma unroll
        for (int nd = 0; nd < 4; ++nd) acc[m][nd] = (f32x4_t){0.f, 0.f, 0.f, 0.f};

    // stage one K+V tile: 8 waves x (1 K-instr + 1 V-instr), 1 KB each.
    // 16B block (row, c) stored at slot c ^ (row&7)  [bank swizzle]
    auto stage = [&](unsigned short* Kd, unsigned short* Vd, int kt) {
        const unsigned short* kSrc = kB + kt * 4096;
        const unsigned short* vSrc = vB + kt * 64;
        int row = w * 8 + (lane >> 3);
        int c   = (lane & 7) ^ (row & 7);
        async16(kSrc + row * 64 + c * 8, Kd + w * 512);
        async16(vSrc + (long)row * S_ + c * 8, Vd + w * 512);
    };

    // one wave's slice of one tile: 32 q-rows x its 32 kv-cols
    auto computeHalf = [&](const unsigned short* Kt, const unsigned short* Vt, bool diag) {
        f32x4_t sc[2][2];
#pragma unroll
        for (int m = 0; m < 2; ++m)
#pragma unroll
            for (int ntl = 0; ntl < 2; ++ntl) sc[m][ntl] = (f32x4_t){0.f, 0.f, 0.f, 0.f};

#pragma unroll
        for (int kk = 0; kk < 2; ++kk)
#pragma unroll
            for (int ntl = 0; ntl < 2; ++ntl) {
                int krow = p * 32 + ntl * 16 + l16;
                bf16x8_t bk = *(const bf16x8_t*)&Kt[krow * 64 +
                                                   (((kk * 4 + quad) ^ (krow & 7)) * 8)];
                sc[0][ntl] = __builtin_amdgcn_mfma_f32_16x16x32_bf16(aQ[0][kk], bk, sc[0][ntl], 0, 0, 0);
                sc[1][ntl] = __builtin_amdgcn_mfma_f32_16x16x32_bf16(aQ[1][kk], bk, sc[1][ntl], 0, 0, 0);
            }

        unsigned short* ssw = Ss[w];
        if (!diag) {
#pragma unroll
            for (int m = 0; m < 2; ++m)
#pragma unroll
                for (int ntl = 0; ntl < 2; ++ntl)
#pragma unroll
                    for (int r = 0; r < 4; ++r)
                        ssw[(m * 16 + quad * 4 + r) * SST + ntl * 16 + l16] = f2bf(sc[m][ntl][r]);
        } else {   // p == odd triangular case: keep iff (quad*4+r) + (m-ntl)*16 >= l16
#pragma unroll
            for (int m = 0; m < 2; ++m)
#pragma unroll
                for (int ntl = 0; ntl < 2; ++ntl) {
                    int dlt = (m - ntl) * 16;
#pragma unroll
                    for (int r = 0; r < 4; ++r) {
                        int rr = quad * 4 + r;
                        float v = ((rr + dlt) >= l16) ? sc[m][ntl][r] : 0.0f;
                        ssw[(m * 16 + rr) * SST + ntl * 16 + l16] = f2bf(v);
                    }
                }
        }

        // PV: A = wave's 16x32 score strips, B = V^T chunks (kv-half p)
        bf16x8_t aS0 = *(const bf16x8_t*)&ssw[(0 * 16 + l16) * SST + quad * 8];
        bf16x8_t aS1 = *(const bf16x8_t*)&ssw[(1 * 16 + l16) * SST + quad * 8];
#pragma unroll
        for (int nd = 0; nd < 4; ++nd) {
            int vrow = nd * 16 + l16;
            bf16x8_t bv = *(const bf16x8_t*)&Vt[vrow * 64 +
                                               (((p * 4 + quad) ^ (vrow & 7)) * 8)];
            acc[0][nd] = __builtin_amdgcn_mfma_f32_16x16x32_bf16(aS0, bv, acc[0][nd], 0, 0, 0);
            acc[1][nd] = __builtin_amdgcn_mfma_f32_16x16x32_bf16(aS1, bv, acc[1][nd], 0, 0, 0);
        }
    };

    // wave computes tile kt iff kt < dkt, or kt == dkt and p <= odd
    // (p > odd: its kv-half is entirely above the diagonal -> all zero)
    stage(K0, V0, 0);
    for (int kt = 0; kt < kvend; kt += 2) {
        stage(K1, V1, kt + 1);
        WAITV2;                       // own tile-kt DMAs done; kt+1 stays in flight
        BAR;
        if (kt < dkt || (kt == dkt && p <= odd)) computeHalf(K0, V0, kt == dkt && p == odd);
        BAR;

        if (kt + 2 < kvend) { stage(K0, V0, kt + 2); WAITV2; }
        else                { WAITV0; }
        BAR;
        if (kt + 1 < dkt || (kt + 1 == dkt && p <= odd))
            computeHalf(K1, V1, kt + 1 == dkt && p == odd);
        BAR;
    }

    // ---- reduce the two kv-half partials (overlay scratch on dead K/V buffers) ----
    float* red = (float*)KV;          // 8192 floats; 2048 per qw
    if (p == 1) {
#pragma unroll
        for (int m = 0; m < 2; ++m)
#pragma unroll
            for (int nd = 0; nd < 4; ++nd)
#pragma unroll
                for (int r = 0; r < 4; ++r)
                    red[qw * 2048 + (m * 16 + quad * 4 + r) * 64 + nd * 16 + l16] = acc[m][nd][r];
    }
    BAR;
    if (p == 0) {
#pragma unroll
        for (int m = 0; m < 2; ++m)
#pragma unroll
            for (int nd = 0; nd < 4; ++nd)
#pragma unroll
                for (int r = 0; r < 4; ++r) {
                    int row = q0w + m * 16 + quad * 4 + r;
                    float v = acc[m][nd][r] +
                              red[qw * 2048 + (m * 16 + quad * 4 + r) * 64 + nd * 16 + l16];
                    out[((long)(b * S_ + row)) * 1024 + hh * 64 + nd * 16 + l16] = v;
                }
    }
}

extern "C" void kernel_launch(void* const* d_in, const int* in_sizes, int n_in,
                              void* d_out, int out_size, void* d_ws, size_t ws_size,
                              hipStream_t stream) {
    const float* Q = (const float*)d_in[0];
    const float* K = (const float*)d_in[1];
    const float* V = (const float*)d_in[2];
    float* out = (float*)d_out;

    const size_t perBuf = (size_t)B_ * H_ * S_ * D_;
    unsigned short* qb = (unsigned short*)d_ws;
    unsigned short* kb = qb + perBuf;
    unsigned short* vt = kb + perBuf;

    hipLaunchKernelGGL(prep_kernel, dim3(512), dim3(256), 0, stream, Q, K, V, qb, kb, vt);
    hipLaunchKernelGGL(retention_kernel, dim3(512), dim3(512), 0, stream, qb, kb, vt, out);
}